// Round 1
// baseline (433.574 us; speedup 1.0000x reference)
//
#include <hip/hip_runtime.h>

#define CH   16
#define HID  128
#define PERC 64
#define DIM  64
#define NVOX (4 * DIM * DIM * DIM)

__global__ __launch_bounds__(256) void nca_pass1(
    const float* __restrict__ x,  const float* __restrict__ w1,
    const float* __restrict__ b1, const float* __restrict__ w2,
    const float* __restrict__ b2, const float* __restrict__ ru,
    float* __restrict__ out, float* __restrict__ alpha_new,
    float* __restrict__ pre_life)
{
    __shared__ __align__(16) float sw1t[PERC * HID];  // [o][c] transposed
    __shared__ __align__(16) float sw2[HID * CH];     // [o][c]
    __shared__ float sb1[HID];
    __shared__ float sb2[CH];

    for (int i = threadIdx.x; i < PERC * HID; i += 256) {
        int c = i >> 7, o = i & 127;           // w1 is [c][o]
        sw1t[o * PERC + c] = w1[i];
    }
    for (int i = threadIdx.x; i < HID * CH; i += 256) sw2[i] = w2[i];
    if (threadIdx.x < HID) sb1[threadIdx.x] = b1[threadIdx.x];
    if (threadIdx.x < CH)  sb2[threadIdx.x] = b2[threadIdx.x];
    __syncthreads();

    const int idx = blockIdx.x * 256 + threadIdx.x;
    const int wx = idx & 63;
    const int hy = (idx >> 6) & 63;
    const int dz = (idx >> 12) & 63;

    float y[PERC];
    #pragma unroll
    for (int j = 0; j < PERC; j++) y[j] = 0.0f;

    float pre_max = -1e30f;

    constexpr float A3[3] = {1.0f, 0.0f, -1.0f};
    constexpr float S3[3] = {1.0f, 2.0f, 1.0f};

    // ---- perception: depthwise 3x3x3 (ident + sobel x/y/z), zero padding ----
    #pragma unroll
    for (int i = 0; i < 3; i++) {
        #pragma unroll
        for (int j = 0; j < 3; j++) {
            #pragma unroll
            for (int k = 0; k < 3; k++) {
                const int zz = dz + i - 1, yy = hy + j - 1, xx = wx + k - 1;
                const bool ok = ((unsigned)zz < 64u) && ((unsigned)yy < 64u) &&
                                ((unsigned)xx < 64u);
                if (ok) {
                    const int nidx = idx + (i - 1) * 4096 + (j - 1) * 64 + (k - 1);
                    const float4* p = (const float4*)(x + (size_t)nidx * CH);
                    const float4 v0 = p[0], v1 = p[1], v2 = p[2], v3 = p[3];
                    const float v[CH] = {v0.x, v0.y, v0.z, v0.w,
                                         v1.x, v1.y, v1.z, v1.w,
                                         v2.x, v2.y, v2.z, v2.w,
                                         v3.x, v3.y, v3.z, v3.w};
                    // kernel is cross-correlation: tap (i,j,k), weights below
                    const float wxw = A3[i] * S3[j] * S3[k] * (1.0f / 32.0f);
                    const float wyw = A3[j] * S3[i] * S3[k] * (1.0f / 32.0f);
                    const float wzw = A3[k] * S3[j] * S3[i] * (1.0f / 32.0f);
                    pre_max = fmaxf(pre_max, v[3]);   // alpha channel = 3
                    #pragma unroll
                    for (int c = 0; c < CH; c++) {
                        if (i == 1 && j == 1 && k == 1) y[4 * c + 0] = v[c];
                        y[4 * c + 1] = fmaf(wxw, v[c], y[4 * c + 1]);
                        y[4 * c + 2] = fmaf(wyw, v[c], y[4 * c + 2]);
                        y[4 * c + 3] = fmaf(wzw, v[c], y[4 * c + 3]);
                    }
                }
            }
        }
    }

    // ---- MLP: d = relu(y@w1+b1)@w2 + b2, streamed over hidden units ----
    float dacc[CH];
    #pragma unroll
    for (int c = 0; c < CH; c++) dacc[c] = sb2[c];

    for (int o = 0; o < HID; o++) {
        float acc = sb1[o];
        const float4* wr = (const float4*)(sw1t + o * PERC);
        #pragma unroll
        for (int q = 0; q < PERC / 4; q++) {
            const float4 w = wr[q];
            acc = fmaf(y[4 * q + 0], w.x, acc);
            acc = fmaf(y[4 * q + 1], w.y, acc);
            acc = fmaf(y[4 * q + 2], w.z, acc);
            acc = fmaf(y[4 * q + 3], w.w, acc);
        }
        acc = fmaxf(acc, 0.0f);
        const float4* w2r = (const float4*)(sw2 + o * CH);
        #pragma unroll
        for (int q = 0; q < CH / 4; q++) {
            const float4 w = w2r[q];
            dacc[4 * q + 0] = fmaf(acc, w.x, dacc[4 * q + 0]);
            dacc[4 * q + 1] = fmaf(acc, w.y, dacc[4 * q + 1]);
            dacc[4 * q + 2] = fmaf(acc, w.z, dacc[4 * q + 2]);
            dacc[4 * q + 3] = fmaf(acc, w.w, dacc[4 * q + 3]);
        }
    }

    // ---- stochastic residual update ----
    const float mask = (ru[idx] <= 0.5f) ? 1.0f : 0.0f;
    float xn[CH];
    #pragma unroll
    for (int c = 0; c < CH; c++) xn[c] = y[4 * c] + dacc[c] * mask;  // y[4c] = center x

    float4* po = (float4*)(out + (size_t)idx * CH);
    po[0] = make_float4(xn[0],  xn[1],  xn[2],  xn[3]);
    po[1] = make_float4(xn[4],  xn[5],  xn[6],  xn[7]);
    po[2] = make_float4(xn[8],  xn[9],  xn[10], xn[11]);
    po[3] = make_float4(xn[12], xn[13], xn[14], xn[15]);

    alpha_new[idx] = xn[3];
    pre_life[idx]  = (pre_max > 0.1f) ? 1.0f : 0.0f;
}

__global__ __launch_bounds__(256) void nca_pass2(
    const float* __restrict__ alpha_new, const float* __restrict__ pre_life,
    float* __restrict__ out)
{
    const int idx = blockIdx.x * 256 + threadIdx.x;
    const int wx = idx & 63;
    const int hy = (idx >> 6) & 63;
    const int dz = (idx >> 12) & 63;

    float m = -1e30f;
    #pragma unroll
    for (int i = 0; i < 3; i++) {
        const int zz = dz + i - 1;
        if ((unsigned)zz >= 64u) continue;
        #pragma unroll
        for (int j = 0; j < 3; j++) {
            const int yy = hy + j - 1;
            if ((unsigned)yy >= 64u) continue;
            #pragma unroll
            for (int k = 0; k < 3; k++) {
                const int xx = wx + k - 1;
                if ((unsigned)xx >= 64u) continue;
                m = fmaxf(m, alpha_new[idx + (i - 1) * 4096 + (j - 1) * 64 + (k - 1)]);
            }
        }
    }
    const float life = (m > 0.1f && pre_life[idx] > 0.5f) ? 1.0f : 0.0f;

    float4* p = (float4*)(out + (size_t)idx * CH);
    #pragma unroll
    for (int q = 0; q < 4; q++) {
        float4 v = p[q];
        v.x *= life; v.y *= life; v.z *= life; v.w *= life;
        p[q] = v;
    }
}

extern "C" void kernel_launch(void* const* d_in, const int* in_sizes, int n_in,
                              void* d_out, int out_size, void* d_ws, size_t ws_size,
                              hipStream_t stream) {
    const float* x  = (const float*)d_in[0];
    const float* w1 = (const float*)d_in[1];
    const float* b1 = (const float*)d_in[2];
    const float* w2 = (const float*)d_in[3];
    const float* b2 = (const float*)d_in[4];
    const float* ru = (const float*)d_in[5];
    float* out = (float*)d_out;

    float* alpha_new = (float*)d_ws;          // NVOX floats
    float* pre_life  = alpha_new + NVOX;      // NVOX floats  (8 MB total)

    const dim3 grid(NVOX / 256), block(256);
    hipLaunchKernelGGL(nca_pass1, grid, block, 0, stream,
                       x, w1, b1, w2, b2, ru, out, alpha_new, pre_life);
    hipLaunchKernelGGL(nca_pass2, grid, block, 0, stream,
                       alpha_new, pre_life, out);
}

// Round 3
// 386.418 us; speedup vs baseline: 1.1220x; 1.1220x over previous
//
#include <hip/hip_runtime.h>

#define CH   16
#define HID  128
#define DIM  64
#define NVOX (4 * DIM * DIM * DIM)

typedef __attribute__((ext_vector_type(8))) short short8;
typedef __attribute__((ext_vector_type(4))) float f32x4;

__device__ __forceinline__ unsigned short f2bf(float f) {
    union { float f; unsigned int u; } c; c.f = f;
    unsigned int u = c.u;
    u += 0x7FFFu + ((u >> 16) & 1u);          // round-nearest-even
    return (unsigned short)(u >> 16);
}

// One wave = 16 voxels (contiguous in x). Lane l: voxel m=l&15, k-group g=l>>4.
// Lane computes perception features k = 8g+j (K-half 0) and 32+8g+j (K-half 1)
// of voxel m -- exactly the mfma_f32_16x16x32_bf16 A-fragment layout.
__global__ __launch_bounds__(512) void nca_pass1(
    const float* __restrict__ x,  const float* __restrict__ w1,
    const float* __restrict__ b1, const float* __restrict__ w2,
    const float* __restrict__ b2, const float* __restrict__ ru,
    float* __restrict__ out, float* __restrict__ alpha_new,
    float* __restrict__ pre_life)
{
    // W1T[o][c] bf16, row stride 72 (144B = 16B-aligned, 2-way banks = free)
    __shared__ __align__(16) unsigned short sW1T[HID * 72];
    // W2T[c][k] bf16, row stride 136 (272B, 16B-aligned)
    __shared__ __align__(16) unsigned short sW2T[CH * 136];
    // per-wave H tile: 16 rows x 136 stride bf16
    __shared__ __align__(16) unsigned short sH[8 * 16 * 136];
    __shared__ float sb1[HID];
    __shared__ float sb2[CH];

    for (int i = threadIdx.x; i < 64 * HID; i += 512) {
        int c = i >> 7, o = i & 127;          // w1 is [c][o]
        sW1T[o * 72 + c] = f2bf(w1[i]);
    }
    for (int i = threadIdx.x; i < HID * CH; i += 512) {
        int k = i >> 4, c = i & 15;           // w2 is [k][c]
        sW2T[c * 136 + k] = f2bf(w2[i]);
    }
    if (threadIdx.x < HID) sb1[threadIdx.x] = b1[threadIdx.x];
    if (threadIdx.x < CH)  sb2[threadIdx.x] = b2[threadIdx.x];
    __syncthreads();

    const int lane = threadIdx.x & 63;
    const int wid  = threadIdx.x >> 6;
    const int m = lane & 15;
    const int g = lane >> 4;

    const int voxbase = (blockIdx.x * 8 + wid) * 16;
    const int wxb = voxbase & 63;
    const int hy  = (voxbase >> 6) & 63;
    const int dz  = (voxbase >> 12) & 63;
    const int bb  = voxbase >> 18;

    const int c0 = 2 * g;                     // channels c0,c0+1 -> K-half 0
    const int c2 = 8 + 2 * g;                 // channels c2,c2+1 -> K-half 1

    float acc0[8], acc1[8];
    #pragma unroll
    for (int q = 0; q < 8; q++) { acc0[q] = 0.0f; acc1[q] = 0.0f; }
    float pre_max = -1e30f;
    const int wx = wxb + m;

    constexpr float A3[3] = {1.0f, 0.0f, -1.0f};
    constexpr float S3[3] = {1.0f, 2.0f, 1.0f};

    #pragma unroll
    for (int i = 0; i < 3; i++) {
        const int zz = dz + i - 1;
        #pragma unroll
        for (int j = 0; j < 3; j++) {
            const int yy = hy + j - 1;
            const bool okzy = ((unsigned)zz < 64u) && ((unsigned)yy < 64u);
            #pragma unroll
            for (int k = 0; k < 3; k++) {
                const int xx = wx + k - 1;
                const bool ok = okzy && ((unsigned)xx < 64u);
                const size_t base =
                    ((((size_t)bb * 64 + zz) * 64 + yy) * 64 + xx) * CH;
                float2 va = ok ? *(const float2*)(x + base + c0)
                               : make_float2(0.0f, 0.0f);
                float2 vb = ok ? *(const float2*)(x + base + c2)
                               : make_float2(0.0f, 0.0f);
                const float wxw = A3[i] * S3[j] * S3[k] * (1.0f / 32.0f);
                const float wyw = A3[j] * S3[i] * S3[k] * (1.0f / 32.0f);
                const float wzw = A3[k] * S3[j] * S3[i] * (1.0f / 32.0f);
                // channel c0 -> features 8g+0..3, c0+1 -> 8g+4..7
                acc0[1] = fmaf(wxw, va.x, acc0[1]);
                acc0[2] = fmaf(wyw, va.x, acc0[2]);
                acc0[3] = fmaf(wzw, va.x, acc0[3]);
                acc0[5] = fmaf(wxw, va.y, acc0[5]);
                acc0[6] = fmaf(wyw, va.y, acc0[6]);
                acc0[7] = fmaf(wzw, va.y, acc0[7]);
                acc1[1] = fmaf(wxw, vb.x, acc1[1]);
                acc1[2] = fmaf(wyw, vb.x, acc1[2]);
                acc1[3] = fmaf(wzw, vb.x, acc1[3]);
                acc1[5] = fmaf(wxw, vb.y, acc1[5]);
                acc1[6] = fmaf(wyw, vb.y, acc1[6]);
                acc1[7] = fmaf(wzw, vb.y, acc1[7]);
                if (i == 1 && j == 1 && k == 1) {
                    acc0[0] = va.x; acc0[4] = va.y;
                    acc1[0] = vb.x; acc1[4] = vb.y;
                }
                pre_max = fmaxf(pre_max, va.y);   // channel 3 when g==1
            }
        }
    }

    short8 a0, a1;
    #pragma unroll
    for (int q = 0; q < 8; q++) {
        a0[q] = (short)f2bf(acc0[q]);
        a1[q] = (short)f2bf(acc1[q]);
    }

    // ---- stage 1: H = relu(Y @ W1 + b1), 16 MFMA ----
    unsigned short* Hrow = sH + wid * (16 * 136);
    #pragma unroll
    for (int n = 0; n < 8; n++) {
        const float bv = sb1[16 * n + m];
        f32x4 h = {bv, bv, bv, bv};
        const short8 bk0 = *(const short8*)(sW1T + (16 * n + m) * 72 + 8 * g);
        const short8 bk1 = *(const short8*)(sW1T + (16 * n + m) * 72 + 32 + 8 * g);
        h = __builtin_amdgcn_mfma_f32_16x16x32_bf16(a0, bk0, h, 0, 0, 0);
        h = __builtin_amdgcn_mfma_f32_16x16x32_bf16(a1, bk1, h, 0, 0, 0);
        #pragma unroll
        for (int r = 0; r < 4; r++) {
            // D layout: row = 4g+r (voxel), col = 16n+m (hidden)
            Hrow[(4 * g + r) * 136 + 16 * n + m] = f2bf(fmaxf(h[r], 0.0f));
        }
    }

    // ---- stage 2: D = H @ W2 + b2, 4 MFMA ----
    const float bv2 = sb2[m];
    f32x4 d = {bv2, bv2, bv2, bv2};
    #pragma unroll
    for (int s = 0; s < 4; s++) {
        const short8 a2 = *(const short8*)(Hrow + m * 136 + 32 * s + 8 * g);
        const short8 bf = *(const short8*)(sW2T + m * 136 + 32 * s + 8 * g);
        d = __builtin_amdgcn_mfma_f32_16x16x32_bf16(a2, bf, d, 0, 0, 0);
    }

    // ---- epilogue: residual update; lane handles voxels 4g+r, channel m ----
    #pragma unroll
    for (int r = 0; r < 4; r++) {
        const size_t v = (size_t)voxbase + 4 * g + r;
        const float xc = x[v * CH + m];
        const float mask = (ru[v] <= 0.5f) ? 1.0f : 0.0f;
        const float xn = fmaf(d[r], mask, xc);
        out[v * CH + m] = xn;
        if (m == 3) alpha_new[v] = xn;
    }
    if (g == 1) pre_life[voxbase + m] = (pre_max > 0.1f) ? 1.0f : 0.0f;
}

__global__ __launch_bounds__(256) void nca_pass2(
    const float* __restrict__ alpha_new, const float* __restrict__ pre_life,
    float* __restrict__ out)
{
    const int idx = blockIdx.x * 256 + threadIdx.x;
    const int wx = idx & 63;
    const int hy = (idx >> 6) & 63;
    const int dz = (idx >> 12) & 63;

    float m = -1e30f;
    #pragma unroll
    for (int i = 0; i < 3; i++) {
        const int zz = dz + i - 1;
        if ((unsigned)zz >= 64u) continue;
        #pragma unroll
        for (int j = 0; j < 3; j++) {
            const int yy = hy + j - 1;
            if ((unsigned)yy >= 64u) continue;
            #pragma unroll
            for (int k = 0; k < 3; k++) {
                const int xx = wx + k - 1;
                if ((unsigned)xx >= 64u) continue;
                m = fmaxf(m, alpha_new[idx + (i - 1) * 4096 + (j - 1) * 64 + (k - 1)]);
            }
        }
    }
    const float life = (m > 0.1f && pre_life[idx] > 0.5f) ? 1.0f : 0.0f;

    float4* p = (float4*)(out + (size_t)idx * CH);
    #pragma unroll
    for (int q = 0; q < 4; q++) {
        float4 v = p[q];
        v.x *= life; v.y *= life; v.z *= life; v.w *= life;
        p[q] = v;
    }
}

extern "C" void kernel_launch(void* const* d_in, const int* in_sizes, int n_in,
                              void* d_out, int out_size, void* d_ws, size_t ws_size,
                              hipStream_t stream) {
    const float* x  = (const float*)d_in[0];
    const float* w1 = (const float*)d_in[1];
    const float* b1 = (const float*)d_in[2];
    const float* w2 = (const float*)d_in[3];
    const float* b2 = (const float*)d_in[4];
    const float* ru = (const float*)d_in[5];
    float* out = (float*)d_out;

    float* alpha_new = (float*)d_ws;
    float* pre_life  = alpha_new + NVOX;

    hipLaunchKernelGGL(nca_pass1, dim3(NVOX / 128), dim3(512), 0, stream,
                       x, w1, b1, w2, b2, ru, out, alpha_new, pre_life);
    hipLaunchKernelGGL(nca_pass2, dim3(NVOX / 256), dim3(256), 0, stream,
                       alpha_new, pre_life, out);
}